// Round 3
// baseline (109.415 us; speedup 1.0000x reference)
//
#include <hip/hip_runtime.h>

#define NN 4096
#define MM 4096
#define NEG 0.01f

#define SLABS 4          // column split (K-split)
#define SLABW 1024       // columns per slab
#define RPB 16           // rows per block
#define RPW 4            // rows per wave

// Phase 1: partial GEMV. Grid = (NN/RPB) * SLABS = 256*4 = 1024 blocks (4/CU).
// part layout: part[sb*NN + row] = float2(s1_partial, s2_partial)
__global__ __launch_bounds__(256, 4) void partial_kernel(
    const float* __restrict__ W,
    const float* __restrict__ l0,
    const float* __restrict__ u0,
    float2* __restrict__ part)
{
    __shared__ float s_c[SLABW];
    __shared__ float s_r[SLABW];

    const int sb   = blockIdx.x & (SLABS - 1);
    const int rb   = blockIdx.x >> 2;
    const int col0 = sb * SLABW;

    // Stage this slab's c/r (1024 floats each): one float4 per thread.
    {
        const int j = threadIdx.x * 4;
        const float4 l = *(const float4*)(l0 + col0 + j);
        const float4 u = *(const float4*)(u0 + col0 + j);
        *(float4*)(s_c + j) = make_float4(0.5f*(l.x+u.x), 0.5f*(l.y+u.y),
                                          0.5f*(l.z+u.z), 0.5f*(l.w+u.w));
        *(float4*)(s_r + j) = make_float4(0.5f*(u.x-l.x), 0.5f*(u.y-l.y),
                                          0.5f*(u.z-l.z), 0.5f*(u.w-l.w));
    }
    __syncthreads();

    const int wave = threadIdx.x >> 6;
    const int lane = threadIdx.x & 63;
    const int row0 = rb * RPB + wave * RPW;

    // Preload this lane's c/r slices into registers: cols t*256 + lane*4.
    float4 cc[4], rr[4];
    #pragma unroll
    for (int t = 0; t < 4; ++t) {
        cc[t] = *(const float4*)(s_c + t * 256 + lane * 4);
        rr[t] = *(const float4*)(s_r + t * 256 + lane * 4);
    }

    float s1[RPW] = {0.f, 0.f, 0.f, 0.f};
    float s2[RPW] = {0.f, 0.f, 0.f, 0.f};

    // 16 independent float4 W-loads, no LDS in the loop, no serial chain
    // across loads: pure stream + FMA.
    #pragma unroll
    for (int k = 0; k < RPW; ++k) {
        const float* __restrict__ Wr = W + (size_t)(row0 + k) * MM + col0;
        #pragma unroll
        for (int t = 0; t < 4; ++t) {
            const float4 w = *(const float4*)(Wr + t * 256 + lane * 4);
            s1[k] += w.x * cc[t].x + w.y * cc[t].y +
                     w.z * cc[t].z + w.w * cc[t].w;
            s2[k] += fabsf(w.x) * rr[t].x + fabsf(w.y) * rr[t].y +
                     fabsf(w.z) * rr[t].z + fabsf(w.w) * rr[t].w;
        }
    }

    // Butterfly reduce 8 accumulators across the 64-lane wave.
    #pragma unroll
    for (int off = 32; off > 0; off >>= 1) {
        #pragma unroll
        for (int k = 0; k < RPW; ++k) {
            s1[k] += __shfl_down(s1[k], off);
            s2[k] += __shfl_down(s2[k], off);
        }
    }

    if (lane == 0) {
        #pragma unroll
        for (int k = 0; k < RPW; ++k)
            part[sb * NN + row0 + k] = make_float2(s1[k], s2[k]);
    }
}

// Phase 2: sum slab partials + leaky-relu relaxation epilogue.
// Grid = NN/256 = 16 blocks.
__global__ __launch_bounds__(256) void epilogue_kernel(
    const float2* __restrict__ part,
    const float* __restrict__ lbnd,
    const float* __restrict__ ubnd,
    const float* __restrict__ alpha,
    const float* __restrict__ b,
    float* __restrict__ out)
{
    const int row = blockIdx.x * 256 + threadIdx.x;

    float s1 = 0.f, s2 = 0.f;
    #pragma unroll
    for (int sb = 0; sb < SLABS; ++sb) {
        const float2 p = part[sb * NN + row];
        s1 += p.x;
        s2 += p.y;
    }

    const float L = lbnd[row];
    const float U = ubnd[row];
    const float A = alpha[row];
    const float B = b[row];

    float lw = NEG, uw = NEG, ub_bias = 0.0f;
    if (L > 0.0f) {
        lw = 1.0f; uw = 1.0f;
    } else if (L < 0.0f && U > 0.0f) {
        const float slope = (U - NEG * L) / (U - L);
        uw = slope;
        ub_bias = (NEG - slope) * L;   // crossing-neuron upper intercept
        lw = fminf(fmaxf(A, NEG), 1.0f);
    }

    const float Pu = s1 + s2;   // max(W,0)@u0 + min(W,0)@l0
    const float Pl = s1 - s2;   // max(W,0)@l0 + min(W,0)@u0
    out[row]      = lw * (Pl + B);             // lower
    out[NN + row] = uw * (Pu + B) + ub_bias;   // upper
}

extern "C" void kernel_launch(void* const* d_in, const int* in_sizes, int n_in,
                              void* d_out, int out_size, void* d_ws, size_t ws_size,
                              hipStream_t stream) {
    const float* lbnd  = (const float*)d_in[0];
    const float* ubnd  = (const float*)d_in[1];
    const float* alpha = (const float*)d_in[2];
    const float* W     = (const float*)d_in[3];
    const float* b     = (const float*)d_in[4];
    const float* l0    = (const float*)d_in[5];
    const float* u0    = (const float*)d_in[6];
    float* out   = (float*)d_out;
    float2* part = (float2*)d_ws;   // SLABS*NN float2 = 128 KB, every slot
                                    // written by partial_kernel before read.

    partial_kernel<<<(NN / RPB) * SLABS, 256, 0, stream>>>(W, l0, u0, part);
    epilogue_kernel<<<NN / 256, 256, 0, stream>>>(part, lbnd, ubnd, alpha, b, out);
}

// Round 4
// 103.509 us; speedup vs baseline: 1.0571x; 1.0571x over previous
//
#include <hip/hip_runtime.h>

#define NN 4096
#define MM 4096
#define NEG 0.01f

// Single kernel: 4 waves/block, one row of W per wave.
// Grid = 1024 blocks -> 4 blocks/CU, 16 waves/CU.
// Hot loop fully unrolled: 16 independent float4 W loads per row,
// dual accumulator pairs to break the serial FMA dependence chain.
__global__ __launch_bounds__(256, 4) void abstract_leaky_relu_kernel(
    const float* __restrict__ lbnd,
    const float* __restrict__ ubnd,
    const float* __restrict__ alpha,
    const float* __restrict__ W,
    const float* __restrict__ b,
    const float* __restrict__ l0,
    const float* __restrict__ u0,
    float* __restrict__ out)
{
    __shared__ float s_c[MM];
    __shared__ float s_r[MM];

    for (int j = threadIdx.x * 4; j < MM; j += 256 * 4) {
        const float4 l = *(const float4*)(l0 + j);
        const float4 u = *(const float4*)(u0 + j);
        *(float4*)(s_c + j) = make_float4(0.5f*(l.x+u.x), 0.5f*(l.y+u.y),
                                          0.5f*(l.z+u.z), 0.5f*(l.w+u.w));
        *(float4*)(s_r + j) = make_float4(0.5f*(u.x-l.x), 0.5f*(u.y-l.y),
                                          0.5f*(u.z-l.z), 0.5f*(u.w-l.w));
    }
    __syncthreads();

    const int wave = threadIdx.x >> 6;
    const int lane = threadIdx.x & 63;
    const int row  = (blockIdx.x << 2) + wave;

    const float* __restrict__ Wr = W + (size_t)row * MM;
    const int base = lane * 4;

    float s1a = 0.f, s1b = 0.f, s2a = 0.f, s2b = 0.f;

    #pragma unroll
    for (int t = 0; t < 16; ++t) {
        const int j = base + t * 256;
        const float4 w = *(const float4*)(Wr + j);
        const float4 c = *(const float4*)(s_c + j);
        const float4 r = *(const float4*)(s_r + j);
        if (t & 1) {
            s1b += w.x * c.x + w.y * c.y + w.z * c.z + w.w * c.w;
            s2b += fabsf(w.x) * r.x + fabsf(w.y) * r.y +
                   fabsf(w.z) * r.z + fabsf(w.w) * r.w;
        } else {
            s1a += w.x * c.x + w.y * c.y + w.z * c.z + w.w * c.w;
            s2a += fabsf(w.x) * r.x + fabsf(w.y) * r.y +
                   fabsf(w.z) * r.z + fabsf(w.w) * r.w;
        }
    }

    float s1 = s1a + s1b;
    float s2 = s2a + s2b;

    #pragma unroll
    for (int off = 32; off > 0; off >>= 1) {
        s1 += __shfl_down(s1, off);
        s2 += __shfl_down(s2, off);
    }

    if (lane == 0) {
        const float L = lbnd[row];
        const float U = ubnd[row];
        const float A = alpha[row];
        const float B = b[row];

        float lw = NEG, uw = NEG, ub_bias = 0.0f;
        if (L > 0.0f) {
            lw = 1.0f; uw = 1.0f;
        } else if (L < 0.0f && U > 0.0f) {
            const float slope = (U - NEG * L) / (U - L);
            uw = slope;
            ub_bias = (NEG - slope) * L;   // crossing-neuron upper intercept
            lw = fminf(fmaxf(A, NEG), 1.0f);
        }

        const float Pu = s1 + s2;   // max(W,0)@u0 + min(W,0)@l0
        const float Pl = s1 - s2;   // max(W,0)@l0 + min(W,0)@u0
        out[row]      = lw * (Pl + B);             // lower
        out[NN + row] = uw * (Pu + B) + ub_bias;   // upper
    }
}

extern "C" void kernel_launch(void* const* d_in, const int* in_sizes, int n_in,
                              void* d_out, int out_size, void* d_ws, size_t ws_size,
                              hipStream_t stream) {
    const float* lbnd  = (const float*)d_in[0];
    const float* ubnd  = (const float*)d_in[1];
    const float* alpha = (const float*)d_in[2];
    const float* W     = (const float*)d_in[3];
    const float* b     = (const float*)d_in[4];
    const float* l0    = (const float*)d_in[5];
    const float* u0    = (const float*)d_in[6];
    float* out = (float*)d_out;

    abstract_leaky_relu_kernel<<<NN / 4, 256, 0, stream>>>(
        lbnd, ubnd, alpha, W, b, l0, u0, out);
}